// Round 9
// baseline (380.610 us; speedup 1.0000x reference)
//
#include <hip/hip_runtime.h>
#include <hip/hip_bf16.h>
#include <math.h>

#define N_FEAT 32
#define N_HID  64   // 2*N_FEAT
#define N_LAT  64
#define R_HID  128  // 2*N_LAT
#define TILES_PER_WAVE 8    // 128 tracks/wave -> 15625 waves (4 pairs/wave)
#define LDSW 68             // padded f32 row stride for h1 tile (2-way conflicts only)

typedef short s16x8 __attribute__((ext_vector_type(8)));
typedef float f32x4 __attribute__((ext_vector_type(4)));
typedef int   i32x4 __attribute__((ext_vector_type(4)));

__device__ __forceinline__ short bfs(float f) {          // f32 -> bf16 bits (RNE)
    __bf16 b = (__bf16)f;
    return __builtin_bit_cast(short, b);
}
__device__ __forceinline__ float bff(short s) {          // bf16 bits -> f32 (exact)
    return (float)__builtin_bit_cast(__bf16, s);
}
__device__ __forceinline__ f32x4 mfma16(s16x8 a, s16x8 b, f32x4 c) {
    return __builtin_amdgcn_mfma_f32_16x16x32_bf16(a, b, c, 0, 0, 0);
}
__device__ __forceinline__ float rdlane(float v, int l) {
    return __int_as_float(__builtin_amdgcn_readlane(__float_as_int(v), l));
}
__device__ __forceinline__ void split8(f32x4 a, f32x4 b, s16x8& h, s16x8& l) {
    #pragma unroll
    for (int j = 0; j < 4; ++j) {
        short h0 = bfs(a[j]); h[j] = h0;     l[j] = bfs(a[j] - bff(h0));
        short h1 = bfs(b[j]); h[4 + j] = h1; l[4 + j] = bfs(b[j] - bff(h1));
    }
}

// ---------------------------------------------------------------------------
// phi via bf16 MFMA, hi/lo split (absmax-verified 0.0039 across rounds 6-8).
// Round-8 lesson: unified VGPR+AGPR (~160) caps residency at 3 waves/SIMD;
// issue density per wave is the lever now. This round: 2-tile ILP (A,B
// interleaved so B's work hides A's LDS/MFMA latency) + ALL weight frags
// (W1+W2, 24 frags = 24 KB) in LDS to pay for the extra live state.
// wfrag reads are kept per-tile (not LICM-hoisted into 96 regs) via an
// opaque `dyn` offset. Single h1 slice per wave reused A-then-B: DS ops are
// in-order per wave, and the compiler sees the address aliasing.
// MFMA layouts (m89/m91-verified): A: row=l&15, k=8*(l>>4)+j; B: col=l&15,
// k=8*(l>>4)+j; C/D: col=l&15, row=4*(l>>4)+reg.
// ---------------------------------------------------------------------------
__global__ __launch_bounds__(256, 3) void phi_mfma_kernel(
    const float* __restrict__ x,
    const int*   __restrict__ eids,
    const float* __restrict__ w1, const float* __restrict__ b1,
    const float* __restrict__ w2, const float* __restrict__ b2,
    float* __restrict__ pooled, int n_tracks)
{
    // frag index map: 0..3 W1hi(n), 4..7 W1lo(n), 8..15 W2hi(4s+n), 16..23 W2lo(4s+n)
    __shared__ s16x8 wfrag[24][64];
    __shared__ float h1lds[4][16 * LDSW];   // one slice per wave, reused A then B

    const int lane = threadIdx.x & 63;
    const int wv   = threadIdx.x >> 6;
    const int g    = lane >> 4;   // 0..3
    const int r    = lane & 15;   // 0..15

    // ---- one-time cooperative pack of all weight frags ----
    #pragma unroll 1
    for (int f = wv; f < 24; f += 4) {
        const float* src; int krow; bool lo; int n;
        if (f < 8) { lo = (f >= 4); n = f & 3; src = w1; krow = 8 * g; }
        else {
            int idx = f - 8; lo = (idx >= 8); idx &= 7;
            n = idx & 3; src = w2; krow = 32 * (idx >> 2) + 8 * g;
        }
        s16x8 v;
        #pragma unroll
        for (int j = 0; j < 8; ++j) {
            float fv = src[(size_t)(krow + j) * 64 + (r + 16 * n)];
            short h  = bfs(fv);
            v[j] = lo ? bfs(fv - bff(h)) : h;
        }
        wfrag[f][lane] = v;
    }
    __syncthreads();

    float* lds = h1lds[wv];
    const long long wbase = ((long long)blockIdx.x * 4 + wv) * (16LL * TILES_PER_WAVE);
    if (wbase >= n_tracks) return;   // after the only barrier -> safe

    float b1v[4], b2v[4];
    #pragma unroll
    for (int n = 0; n < 4; ++n) { b1v[n] = b1[r + 16 * n]; b2v[n] = b2[r + 16 * n]; }

    // x loader: lane (g,r) takes row tb+r, cols 8g..8g+7 (two f32x4)
    #define LOADX(TB, XA, XB) {                                                   \
        long long row_ = (TB) + r; if (row_ > n_tracks - 1) row_ = n_tracks - 1;  \
        XA = *(const f32x4*)(x + row_ * N_FEAT + 8 * g);                          \
        XB = *(const f32x4*)(x + row_ * N_FEAT + 8 * g + 4);                      \
    }
    #define LOADE(TB, E4) {                                                       \
        long long ib_ = (TB) + 4 * g;                                             \
        if (ib_ > n_tracks - 4) ib_ = (n_tracks - 4) & ~3LL;                      \
        E4 = *(const i32x4*)(eids + ib_);                                         \
    }

    // ---- prologue: pair 0 ----
    f32x4 xaA, xbA, xaB, xbB;
    LOADX(wbase, xaA, xbA)
    LOADX(wbase + 16, xaB, xbB)

    float carry[4] = {0.f, 0.f, 0.f, 0.f};
    int carry_id = -1;
    int dyn = 0;   // opaque 0: defeats LICM-hoisting of wfrag reads into regs

    #pragma unroll 1
    for (int p = 0; p < TILES_PER_WAVE / 2; ++p) {
        asm volatile("" : "+v"(dyn));
        const s16x8* wfl = (const s16x8*)&wfrag[0][lane] + dyn;

        long long tbA = wbase + 32LL * p;
        long long tbB = tbA + 16;
        if (tbA >= n_tracks) break;

        i32x4 e4A, e4B;
        LOADE(tbA, e4A)
        LOADE(tbB, e4B)

        // split current pair to bf16 hi/lo A-frags (frees xa*/xb* for prefetch)
        s16x8 xhA, xlA, xhB, xlB;
        split8(xaA, xbA, xhA, xlA);
        split8(xaB, xbB, xhB, xlB);

        const bool pf = (p + 1 < TILES_PER_WAVE / 2) && (tbA + 32 < n_tracks);
        if (pf) { LOADX(tbA + 32, xaA, xbA) LOADX(tbA + 48, xaB, xbB) }

        // ---- layer 1 A (12 MFMA, W1 frags from LDS) ----
        f32x4 h1A[4];
        #pragma unroll
        for (int n = 0; n < 4; ++n) {
            s16x8 wh = wfl[64 * n], wl = wfl[64 * (4 + n)];
            f32x4 c = {0.f, 0.f, 0.f, 0.f};
            c = mfma16(xlA, wh, c);
            c = mfma16(xhA, wl, c);
            c = mfma16(xhA, wh, c);
            h1A[n] = c;
        }
        // stage A (bias+relu)
        #pragma unroll
        for (int n = 0; n < 4; ++n)
            #pragma unroll
            for (int q = 0; q < 4; ++q)
                lds[(4 * g + q) * LDSW + r + 16 * n] = fmaxf(h1A[n][q] + b1v[n], 0.f);

        // ---- layer 1 B (overlaps A's LDS latency) ----
        f32x4 h1B[4];
        #pragma unroll
        for (int n = 0; n < 4; ++n) {
            s16x8 wh = wfl[64 * n], wl = wfl[64 * (4 + n)];
            f32x4 c = {0.f, 0.f, 0.f, 0.f};
            c = mfma16(xlB, wh, c);
            c = mfma16(xhB, wl, c);
            c = mfma16(xhB, wh, c);
            h1B[n] = c;
        }

        // read A's h1 A-frags (issued before stage-B; DS is in-order per wave)
        f32x4 avA0 = *(const f32x4*)&lds[r * LDSW + 8 * g];
        f32x4 bvA0 = *(const f32x4*)&lds[r * LDSW + 8 * g + 4];
        f32x4 avA1 = *(const f32x4*)&lds[r * LDSW + 32 + 8 * g];
        f32x4 bvA1 = *(const f32x4*)&lds[r * LDSW + 32 + 8 * g + 4];

        // stage B into the same slice (in-order DS: read-A completes first)
        #pragma unroll
        for (int n = 0; n < 4; ++n)
            #pragma unroll
            for (int q = 0; q < 4; ++q)
                lds[(4 * g + q) * LDSW + r + 16 * n] = fmaxf(h1B[n][q] + b1v[n], 0.f);

        // ---- layer 2 A (24 MFMA, W2 frags from LDS) ----
        f32x4 h2A[4] = {{0.f,0.f,0.f,0.f},{0.f,0.f,0.f,0.f},{0.f,0.f,0.f,0.f},{0.f,0.f,0.f,0.f}};
        {
            s16x8 ah, al;
            split8(avA0, bvA0, ah, al);
            #pragma unroll
            for (int n = 0; n < 4; ++n) {
                s16x8 wh = wfl[64 * (8 + n)], wl = wfl[64 * (16 + n)];
                h2A[n] = mfma16(al, wh, h2A[n]);
                h2A[n] = mfma16(ah, wl, h2A[n]);
                h2A[n] = mfma16(ah, wh, h2A[n]);
            }
            split8(avA1, bvA1, ah, al);
            #pragma unroll
            for (int n = 0; n < 4; ++n) {
                s16x8 wh = wfl[64 * (12 + n)], wl = wfl[64 * (20 + n)];
                h2A[n] = mfma16(al, wh, h2A[n]);
                h2A[n] = mfma16(ah, wl, h2A[n]);
                h2A[n] = mfma16(ah, wh, h2A[n]);
            }
        }

        // read B's h1 A-frags
        f32x4 avB0 = *(const f32x4*)&lds[r * LDSW + 8 * g];
        f32x4 bvB0 = *(const f32x4*)&lds[r * LDSW + 8 * g + 4];
        f32x4 avB1 = *(const f32x4*)&lds[r * LDSW + 32 + 8 * g];
        f32x4 bvB1 = *(const f32x4*)&lds[r * LDSW + 32 + 8 * g + 4];

        // ---- pool A (bias+relu+run-carry) ----
        #define POOL_TILE(H2, E4, TB) {                                                   \
            const int rem = (int)((n_tracks - (TB) < 16) ? (n_tracks - (TB)) : 16);       \
            const bool newrun   = ((E4)[0] != carry_id);                                  \
            const bool doflush0 = newrun && (carry_id >= 0);                              \
            const bool q01 = ((E4)[1] != (E4)[0]);                                        \
            const bool q12 = ((E4)[2] != (E4)[1]);                                        \
            const bool q23 = ((E4)[3] != (E4)[2]);                                        \
            _Pragma("unroll")                                                             \
            for (int n = 0; n < 4; ++n) {                                                 \
                f32x4 hv;                                                                 \
                _Pragma("unroll")                                                         \
                for (int q = 0; q < 4; ++q) {                                             \
                    float fq = fmaxf(H2[n][q] + b2v[n], 0.f);                             \
                    hv[q] = (4 * g + q < rem) ? fq : 0.f;                                 \
                }                                                                         \
                float* pp = pooled + (size_t)(r + 16 * n);                                \
                float c = carry[n];                                                       \
                if (doflush0) atomicAdd(pp + (size_t)carry_id * N_LAT, c);                \
                if (newrun)   c = 0.f;                                                    \
                c += hv[0];                                                               \
                if (q01) { atomicAdd(pp + (size_t)(E4)[0] * N_LAT, c); c = 0.f; }         \
                c += hv[1];                                                               \
                if (q12) { atomicAdd(pp + (size_t)(E4)[1] * N_LAT, c); c = 0.f; }         \
                c += hv[2];                                                               \
                if (q23) { atomicAdd(pp + (size_t)(E4)[2] * N_LAT, c); c = 0.f; }         \
                c += hv[3];                                                               \
                carry[n] = c;                                                             \
            }                                                                             \
            carry_id = (E4)[3];                                                           \
        }
        POOL_TILE(h2A, e4A, tbA)

        // ---- layer 2 B ----
        f32x4 h2B[4] = {{0.f,0.f,0.f,0.f},{0.f,0.f,0.f,0.f},{0.f,0.f,0.f,0.f},{0.f,0.f,0.f,0.f}};
        {
            s16x8 ah, al;
            split8(avB0, bvB0, ah, al);
            #pragma unroll
            for (int n = 0; n < 4; ++n) {
                s16x8 wh = wfl[64 * (8 + n)], wl = wfl[64 * (16 + n)];
                h2B[n] = mfma16(al, wh, h2B[n]);
                h2B[n] = mfma16(ah, wl, h2B[n]);
                h2B[n] = mfma16(ah, wh, h2B[n]);
            }
            split8(avB1, bvB1, ah, al);
            #pragma unroll
            for (int n = 0; n < 4; ++n) {
                s16x8 wh = wfl[64 * (12 + n)], wl = wfl[64 * (20 + n)];
                h2B[n] = mfma16(al, wh, h2B[n]);
                h2B[n] = mfma16(ah, wl, h2B[n]);
                h2B[n] = mfma16(ah, wh, h2B[n]);
            }
        }

        // ---- pool B ----
        POOL_TILE(h2B, e4B, tbB)
        #undef POOL_TILE
    }

    if (carry_id >= 0) {
        #pragma unroll
        for (int n = 0; n < 4; ++n)
            atomicAdd(pooled + (size_t)carry_id * N_LAT + r + 16 * n, carry[n]);
    }
    #undef LOADX
    #undef LOADE
}

// ---------------------------------------------------------------------------
// rho, wave-parallel (unchanged): one wave = 8 events; lane j owns output j
// (and j+64 in layer 1); weights from LDS, broadcasts via readlane.
// ---------------------------------------------------------------------------
__global__ __launch_bounds__(256) void rho_kernel(
    const float* __restrict__ pooled,
    const float* __restrict__ w1, const float* __restrict__ b1,
    const float* __restrict__ w2, const float* __restrict__ b2,
    const float* __restrict__ w3, const float* __restrict__ b3,
    float* __restrict__ out, int n_events)
{
    __shared__ float lw1[N_LAT * R_HID];
    __shared__ float lw2[R_HID * N_LAT];
    __shared__ float lbias[R_HID + N_LAT + N_LAT + 1];
    {
        int tid = threadIdx.x;
        for (int i = tid; i < N_LAT * R_HID; i += 256) lw1[i] = w1[i];
        for (int i = tid; i < R_HID * N_LAT; i += 256) lw2[i] = w2[i];
        if (tid < R_HID) lbias[tid] = b1[tid];
        if (tid < N_LAT) lbias[R_HID + tid] = b2[tid];
        if (tid < N_LAT) lbias[R_HID + N_LAT + tid] = w3[tid];
        if (tid == 0)    lbias[R_HID + 2 * N_LAT] = b3[0];
    }
    __syncthreads();

    const int lane = threadIdx.x & 63;
    const long long ebase = ((long long)blockIdx.x * 4 + (threadIdx.x >> 6)) * 8;
    if (ebase >= n_events) return;

    const float b1va = lbias[lane];
    const float b1vb = lbias[64 + lane];
    const float b2v  = lbias[R_HID + lane];
    const float w3v  = lbias[R_HID + N_LAT + lane];
    const float b3v  = lbias[R_HID + 2 * N_LAT];

    float pe[8];
    #pragma unroll
    for (int i = 0; i < 8; ++i) {
        long long e = ebase + i;
        pe[i] = (e < n_events) ? pooled[e * N_LAT + lane] : 0.f;
    }

    float r1a[8], r1b[8];
    #pragma unroll
    for (int i = 0; i < 8; ++i) { r1a[i] = b1va; r1b[i] = b1vb; }
    #pragma unroll 2
    for (int k = 0; k < N_LAT; ++k) {
        float wA = lw1[k * R_HID + lane];
        float wB = lw1[k * R_HID + 64 + lane];
        #pragma unroll
        for (int i = 0; i < 8; ++i) {
            float s = rdlane(pe[i], k);
            r1a[i] = fmaf(s, wA, r1a[i]);
            r1b[i] = fmaf(s, wB, r1b[i]);
        }
    }
    #pragma unroll
    for (int i = 0; i < 8; ++i) {
        r1a[i] = fmaxf(r1a[i], 0.f);
        r1b[i] = fmaxf(r1b[i], 0.f);
    }

    float r2[8];
    #pragma unroll
    for (int i = 0; i < 8; ++i) r2[i] = b2v;
    #pragma unroll 2
    for (int k = 0; k < 64; ++k) {
        float w = lw2[k * N_LAT + lane];
        #pragma unroll
        for (int i = 0; i < 8; ++i) r2[i] = fmaf(rdlane(r1a[i], k), w, r2[i]);
    }
    #pragma unroll 2
    for (int k = 0; k < 64; ++k) {
        float w = lw2[(64 + k) * N_LAT + lane];
        #pragma unroll
        for (int i = 0; i < 8; ++i) r2[i] = fmaf(rdlane(r1b[i], k), w, r2[i]);
    }

    float zv = 0.f;
    #pragma unroll
    for (int i = 0; i < 8; ++i) {
        float tv = fmaxf(r2[i], 0.f) * w3v;
        #pragma unroll
        for (int off = 32; off >= 1; off >>= 1) tv += __shfl_xor(tv, off, 64);
        zv = (lane == i) ? tv : zv;
    }
    if (lane < 8 && ebase + lane < n_events)
        out[ebase + lane] = 1.f / (1.f + expf(-(zv + b3v)));
}

extern "C" void kernel_launch(void* const* d_in, const int* in_sizes, int n_in,
                              void* d_out, int out_size, void* d_ws, size_t ws_size,
                              hipStream_t stream) {
    const float* x      = (const float*)d_in[0];
    const int*   eids   = (const int*)  d_in[1];
    const float* phi_w1 = (const float*)d_in[2];
    const float* phi_b1 = (const float*)d_in[3];
    const float* phi_w2 = (const float*)d_in[4];
    const float* phi_b2 = (const float*)d_in[5];
    const float* rho_w1 = (const float*)d_in[6];
    const float* rho_b1 = (const float*)d_in[7];
    const float* rho_w2 = (const float*)d_in[8];
    const float* rho_b2 = (const float*)d_in[9];
    const float* rho_w3 = (const float*)d_in[10];
    const float* rho_b3 = (const float*)d_in[11];
    float* out = (float*)d_out;

    int n_tracks = in_sizes[1];
    int n_events = out_size;

    float* pooled = (float*)d_ws;  // [n_events, 64] accumulator
    hipMemsetAsync(pooled, 0, (size_t)n_events * N_LAT * sizeof(float), stream);

    long long tracks_per_wave = 16LL * TILES_PER_WAVE;
    long long waves  = ((long long)n_tracks + tracks_per_wave - 1) / tracks_per_wave;
    int phi_blocks   = (int)((waves + 3) / 4);
    phi_mfma_kernel<<<phi_blocks, 256, 0, stream>>>(
        x, eids, phi_w1, phi_b1, phi_w2, phi_b2, pooled, n_tracks);

    long long ewaves = ((long long)n_events + 7) / 8;
    int rho_blocks = (int)((ewaves + 3) / 4);
    rho_kernel<<<rho_blocks, 256, 0, stream>>>(
        pooled, rho_w1, rho_b1, rho_w2, rho_b2, rho_w3, rho_b3, out, n_events);
}

// Round 10
// 379.663 us; speedup vs baseline: 1.0025x; 1.0025x over previous
//
#include <hip/hip_runtime.h>
#include <hip/hip_bf16.h>
#include <math.h>

#define N_FEAT 32
#define N_HID  64   // 2*N_FEAT
#define N_LAT  64
#define R_HID  128  // 2*N_LAT
#define TILES_PER_WAVE 8    // 128 tracks/wave -> 15625 waves
#define H1W 88              // h1 bf16 row stride in shorts (176B = 11*16B: aligned b128 rows)

typedef short s16x8 __attribute__((ext_vector_type(8)));
typedef float f32x4 __attribute__((ext_vector_type(4)));
typedef int   i32x4 __attribute__((ext_vector_type(4)));

__device__ __forceinline__ short bfs(float f) {          // f32 -> bf16 bits (RNE)
    __bf16 b = (__bf16)f;
    return __builtin_bit_cast(short, b);
}
__device__ __forceinline__ float bff(short s) {          // bf16 bits -> f32 (exact)
    return (float)__builtin_bit_cast(__bf16, s);
}
__device__ __forceinline__ f32x4 mfma16(s16x8 a, s16x8 b, f32x4 c) {
    return __builtin_amdgcn_mfma_f32_16x16x32_bf16(a, b, c, 0, 0, 0);
}
__device__ __forceinline__ float rdlane(float v, int l) {
    return __int_as_float(__builtin_amdgcn_readlane(__float_as_int(v), l));
}
__device__ __forceinline__ void split8(f32x4 a, f32x4 b, s16x8& h, s16x8& l) {
    #pragma unroll
    for (int j = 0; j < 4; ++j) {
        short h0 = bfs(a[j]); h[j] = h0;     l[j] = bfs(a[j] - bff(h0));
        short h1 = bfs(b[j]); h[4 + j] = h1; l[4 + j] = bfs(b[j] - bff(h1));
    }
}

// B-frag loader: lane (g,r), tile col c: b[j] = w[(k0+j)*64 + c], split hi/lo.
__device__ __forceinline__ void load_bfrag(const float* __restrict__ w, int k0, int c,
                                           s16x8& hi, s16x8& lo) {
    #pragma unroll
    for (int j = 0; j < 8; ++j) {
        float f = w[(size_t)(k0 + j) * 64 + c];
        short h = bfs(f);
        hi[j] = h;
        lo[j] = bfs(f - bff(h));
    }
}

// ---------------------------------------------------------------------------
// phi via bf16 MFMA. Precision scheme (round-10): x and ALL weights keep the
// hi/lo split; the h1 intermediate is stored as plain bf16 (dropped h1_lo
// term: adds ~0.1-0.2% relative on h2; absmax was 0.0039 with 5x margin to
// the 0.02 threshold). This collapses the structure:
//   L1 = 12 MFMA (x hi/lo x W1 hi/lo, W1 in 32 regs)
//   h1 staged bf16 [16][88] -> read back as 2 ds_read_b128 = the A-frags
//   L2 = 16 MFMA (ah x W2 hi/lo, W2 frags in 16 KB LDS, anti-LICM'd)
// LDS/tile traffic ~12 KB (was 28 KB); 28 MFMA/tile (was 36); VALU ~160
// (read-side splits eliminated). LDS 27.6 KB -> 5 blocks/CU; regs cap
// occupancy at the 4-waves/SIMD bucket -> 16 waves/CU.
// Fallback if absmax > 0.02: dual-plane bf16 hi/lo staging (+8 MFMA).
// MFMA layouts (m89/m91-verified): A: row=l&15, k=8*(l>>4)+j; B: col=l&15,
// k=8*(l>>4)+j; C/D: col=l&15, row=4*(l>>4)+reg.
// ---------------------------------------------------------------------------
__global__ __launch_bounds__(256, 4) void phi_mfma_kernel(
    const float* __restrict__ x,
    const int*   __restrict__ eids,
    const float* __restrict__ w1, const float* __restrict__ b1,
    const float* __restrict__ w2, const float* __restrict__ b2,
    float* __restrict__ pooled, int n_tracks)
{
    // W2 frags: [4s+n] = hi, [8+4s+n] = lo
    __shared__ s16x8 wfrag[16][64];          // 16 KB
    __shared__ short h1s[4][16 * H1W];       // bf16 h1, 2816 B per wave

    const int lane = threadIdx.x & 63;
    const int wv   = threadIdx.x >> 6;
    const int g    = lane >> 4;   // 0..3
    const int r    = lane & 15;   // 0..15

    // ---- one-time cooperative pack of W2 frags ----
    #pragma unroll
    for (int ff = 0; ff < 4; ++ff) {
        int f   = wv + 4 * ff;
        int idx = f & 7;
        int s   = idx >> 2;
        int n   = idx & 3;
        bool lo = (f >= 8);
        s16x8 v;
        #pragma unroll
        for (int j = 0; j < 8; ++j) {
            float fv = w2[(size_t)(32 * s + 8 * g + j) * 64 + (r + 16 * n)];
            short h  = bfs(fv);
            v[j] = lo ? bfs(fv - bff(h)) : h;
        }
        wfrag[f][lane] = v;
    }
    __syncthreads();

    short* h1w = h1s[wv];
    const long long wbase = ((long long)blockIdx.x * 4 + wv) * (16LL * TILES_PER_WAVE);
    if (wbase >= n_tracks) return;   // after the only barrier -> safe

    // ---- W1 hi/lo frags in VGPRs (32 regs) ----
    s16x8 w1h[4], w1l[4];
    #pragma unroll
    for (int n = 0; n < 4; ++n) load_bfrag(w1, 8 * g, r + 16 * n, w1h[n], w1l[n]);

    float b1v[4], b2v[4];
    #pragma unroll
    for (int n = 0; n < 4; ++n) { b1v[n] = b1[r + 16 * n]; b2v[n] = b2[r + 16 * n]; }

    #define LOADX(TB, XA, XB) {                                                   \
        long long row_ = (TB) + r; if (row_ > n_tracks - 1) row_ = n_tracks - 1;  \
        XA = *(const f32x4*)(x + row_ * N_FEAT + 8 * g);                          \
        XB = *(const f32x4*)(x + row_ * N_FEAT + 8 * g + 4);                      \
    }

    // ---- prologue: tile 0 x ----
    f32x4 xa, xb;
    LOADX(wbase, xa, xb)

    float carry[4] = {0.f, 0.f, 0.f, 0.f};
    int carry_id = -1;
    int dyn = 0;   // opaque 0: keeps wfrag reads per-tile (defeats LICM reg-hoist)

    #pragma unroll 1
    for (int t = 0; t < TILES_PER_WAVE; ++t) {
        long long tb = wbase + 16LL * t;
        if (tb >= n_tracks) break;

        asm volatile("" : "+v"(dyn));
        const s16x8* wfl = (const s16x8*)&wfrag[0][lane] + dyn;

        // event ids for this lane-group's 4-track window
        long long ib = tb + 4 * g; if (ib > n_tracks - 4) ib = (n_tracks - 4) & ~3LL;
        i32x4 e4 = *(const i32x4*)(eids + ib);

        // ---- split current x to hi/lo A-frags; prefetch next tile ----
        s16x8 xh, xl;
        split8(xa, xb, xh, xl);
        const bool pf = (t + 1 < TILES_PER_WAVE) && (tb + 16 < n_tracks);
        if (pf) LOADX(tb + 16, xa, xb)

        // ---- layer 1: 12 MFMA (W1 from regs) ----
        f32x4 h1C[4];
        #pragma unroll
        for (int n = 0; n < 4; ++n) {
            f32x4 c = {0.f, 0.f, 0.f, 0.f};
            c = mfma16(xl, w1h[n], c);
            c = mfma16(xh, w1l[n], c);
            c = mfma16(xh, w1h[n], c);
            h1C[n] = c;
        }

        // ---- bias+relu, stage h1 as bf16 ----
        #pragma unroll
        for (int n = 0; n < 4; ++n)
            #pragma unroll
            for (int q = 0; q < 4; ++q)
                h1w[(4 * g + q) * H1W + r + 16 * n] =
                    bfs(fmaxf(h1C[n][q] + b1v[n], 0.f));

        // ---- read back h1 rows: 2 b128 = ready A-frags (no extraction) ----
        s16x8 ah0 = *(const s16x8*)&h1w[r * H1W + 8 * g];        // k = 0..31
        s16x8 ah1 = *(const s16x8*)&h1w[r * H1W + 32 + 8 * g];   // k = 32..63

        // ---- layer 2: 16 MFMA (W2 hi/lo frags from LDS) ----
        f32x4 h2C[4] = {{0.f,0.f,0.f,0.f},{0.f,0.f,0.f,0.f},{0.f,0.f,0.f,0.f},{0.f,0.f,0.f,0.f}};
        #pragma unroll
        for (int n = 0; n < 4; ++n) {
            h2C[n] = mfma16(ah0, wfl[64 * (8 + n)], h2C[n]);       // lo s0
            h2C[n] = mfma16(ah0, wfl[64 * n],       h2C[n]);       // hi s0
            h2C[n] = mfma16(ah1, wfl[64 * (12 + n)], h2C[n]);      // lo s1
            h2C[n] = mfma16(ah1, wfl[64 * (4 + n)],  h2C[n]);      // hi s1
        }

        // ---- bias+relu+pool with cross-tile run carry ----
        const int rem = (int)((n_tracks - tb < 16) ? (n_tracks - tb) : 16);
        const bool newrun   = (e4[0] != carry_id);
        const bool doflush0 = newrun && (carry_id >= 0);
        const bool q01 = (e4[1] != e4[0]);
        const bool q12 = (e4[2] != e4[1]);
        const bool q23 = (e4[3] != e4[2]);
        #pragma unroll
        for (int n = 0; n < 4; ++n) {
            f32x4 hv;
            #pragma unroll
            for (int q = 0; q < 4; ++q) {
                float fq = fmaxf(h2C[n][q] + b2v[n], 0.f);
                hv[q] = (4 * g + q < rem) ? fq : 0.f;
            }
            float* pp = pooled + (size_t)(r + 16 * n);
            float c = carry[n];
            if (doflush0) atomicAdd(pp + (size_t)carry_id * N_LAT, c);
            if (newrun)   c = 0.f;
            c += hv[0];
            if (q01) { atomicAdd(pp + (size_t)e4[0] * N_LAT, c); c = 0.f; }
            c += hv[1];
            if (q12) { atomicAdd(pp + (size_t)e4[1] * N_LAT, c); c = 0.f; }
            c += hv[2];
            if (q23) { atomicAdd(pp + (size_t)e4[2] * N_LAT, c); c = 0.f; }
            c += hv[3];
            carry[n] = c;
        }
        carry_id = e4[3];
    }

    if (carry_id >= 0) {
        #pragma unroll
        for (int n = 0; n < 4; ++n)
            atomicAdd(pooled + (size_t)carry_id * N_LAT + r + 16 * n, carry[n]);
    }
    #undef LOADX
}

// ---------------------------------------------------------------------------
// rho, wave-parallel. Round-10 change: 512-thread blocks -> the 66.8 KB LDS
// is shared by 8 waves, 2 blocks/CU = 16 waves/CU (was 8 at 256 threads).
// ---------------------------------------------------------------------------
__global__ __launch_bounds__(512) void rho_kernel(
    const float* __restrict__ pooled,
    const float* __restrict__ w1, const float* __restrict__ b1,
    const float* __restrict__ w2, const float* __restrict__ b2,
    const float* __restrict__ w3, const float* __restrict__ b3,
    float* __restrict__ out, int n_events)
{
    __shared__ float lw1[N_LAT * R_HID];
    __shared__ float lw2[R_HID * N_LAT];
    __shared__ float lbias[R_HID + N_LAT + N_LAT + 1];
    {
        int tid = threadIdx.x;
        for (int i = tid; i < N_LAT * R_HID; i += 512) lw1[i] = w1[i];
        for (int i = tid; i < R_HID * N_LAT; i += 512) lw2[i] = w2[i];
        if (tid < R_HID) lbias[tid] = b1[tid];
        if (tid < N_LAT) lbias[R_HID + tid] = b2[tid];
        if (tid < N_LAT) lbias[R_HID + N_LAT + tid] = w3[tid];
        if (tid == 0)    lbias[R_HID + 2 * N_LAT] = b3[0];
    }
    __syncthreads();

    const int lane = threadIdx.x & 63;
    const long long ebase = ((long long)blockIdx.x * 8 + (threadIdx.x >> 6)) * 8;
    if (ebase >= n_events) return;

    const float b1va = lbias[lane];
    const float b1vb = lbias[64 + lane];
    const float b2v  = lbias[R_HID + lane];
    const float w3v  = lbias[R_HID + N_LAT + lane];
    const float b3v  = lbias[R_HID + 2 * N_LAT];

    float pe[8];
    #pragma unroll
    for (int i = 0; i < 8; ++i) {
        long long e = ebase + i;
        pe[i] = (e < n_events) ? pooled[e * N_LAT + lane] : 0.f;
    }

    float r1a[8], r1b[8];
    #pragma unroll
    for (int i = 0; i < 8; ++i) { r1a[i] = b1va; r1b[i] = b1vb; }
    #pragma unroll 2
    for (int k = 0; k < N_LAT; ++k) {
        float wA = lw1[k * R_HID + lane];
        float wB = lw1[k * R_HID + 64 + lane];
        #pragma unroll
        for (int i = 0; i < 8; ++i) {
            float s = rdlane(pe[i], k);
            r1a[i] = fmaf(s, wA, r1a[i]);
            r1b[i] = fmaf(s, wB, r1b[i]);
        }
    }
    #pragma unroll
    for (int i = 0; i < 8; ++i) {
        r1a[i] = fmaxf(r1a[i], 0.f);
        r1b[i] = fmaxf(r1b[i], 0.f);
    }

    float r2[8];
    #pragma unroll
    for (int i = 0; i < 8; ++i) r2[i] = b2v;
    #pragma unroll 2
    for (int k = 0; k < 64; ++k) {
        float w = lw2[k * N_LAT + lane];
        #pragma unroll
        for (int i = 0; i < 8; ++i) r2[i] = fmaf(rdlane(r1a[i], k), w, r2[i]);
    }
    #pragma unroll 2
    for (int k = 0; k < 64; ++k) {
        float w = lw2[(64 + k) * N_LAT + lane];
        #pragma unroll
        for (int i = 0; i < 8; ++i) r2[i] = fmaf(rdlane(r1b[i], k), w, r2[i]);
    }

    float zv = 0.f;
    #pragma unroll
    for (int i = 0; i < 8; ++i) {
        float tv = fmaxf(r2[i], 0.f) * w3v;
        #pragma unroll
        for (int off = 32; off >= 1; off >>= 1) tv += __shfl_xor(tv, off, 64);
        zv = (lane == i) ? tv : zv;
    }
    if (lane < 8 && ebase + lane < n_events)
        out[ebase + lane] = 1.f / (1.f + expf(-(zv + b3v)));
}

extern "C" void kernel_launch(void* const* d_in, const int* in_sizes, int n_in,
                              void* d_out, int out_size, void* d_ws, size_t ws_size,
                              hipStream_t stream) {
    const float* x      = (const float*)d_in[0];
    const int*   eids   = (const int*)  d_in[1];
    const float* phi_w1 = (const float*)d_in[2];
    const float* phi_b1 = (const float*)d_in[3];
    const float* phi_w2 = (const float*)d_in[4];
    const float* phi_b2 = (const float*)d_in[5];
    const float* rho_w1 = (const float*)d_in[6];
    const float* rho_b1 = (const float*)d_in[7];
    const float* rho_w2 = (const float*)d_in[8];
    const float* rho_b2 = (const float*)d_in[9];
    const float* rho_w3 = (const float*)d_in[10];
    const float* rho_b3 = (const float*)d_in[11];
    float* out = (float*)d_out;

    int n_tracks = in_sizes[1];
    int n_events = out_size;

    float* pooled = (float*)d_ws;  // [n_events, 64] accumulator
    hipMemsetAsync(pooled, 0, (size_t)n_events * N_LAT * sizeof(float), stream);

    long long tracks_per_wave = 16LL * TILES_PER_WAVE;
    long long waves  = ((long long)n_tracks + tracks_per_wave - 1) / tracks_per_wave;
    int phi_blocks   = (int)((waves + 3) / 4);
    phi_mfma_kernel<<<phi_blocks, 256, 0, stream>>>(
        x, eids, phi_w1, phi_b1, phi_w2, phi_b2, pooled, n_tracks);

    long long ewaves = ((long long)n_events + 7) / 8;
    int rho_blocks = (int)((ewaves + 7) / 8);
    rho_kernel<<<rho_blocks, 512, 0, stream>>>(
        pooled, rho_w1, rho_b1, rho_w2, rho_b2, rho_w3, rho_b3, out, n_events);
}

// Round 11
// 217.501 us; speedup vs baseline: 1.7499x; 1.7456x over previous
//
#include <hip/hip_runtime.h>
#include <hip/hip_bf16.h>
#include <math.h>

#define N_FEAT 32
#define N_HID  64   // 2*N_FEAT
#define N_LAT  64
#define R_HID  128  // 2*N_LAT
#define TILES_PER_WAVE 8    // 128 tracks/wave -> 15625 waves
#define STREAM (4 * TILES_PER_WAVE)   // 32 contiguous tracks per lane-group
#define H1W 88              // h1 bf16 row stride in shorts (176B, aligned b128 rows)

typedef short s16x8 __attribute__((ext_vector_type(8)));
typedef float f32x4 __attribute__((ext_vector_type(4)));
typedef int   i32x4 __attribute__((ext_vector_type(4)));

__device__ __forceinline__ short bfs(float f) {          // f32 -> bf16 bits (RNE)
    __bf16 b = (__bf16)f;
    return __builtin_bit_cast(short, b);
}
__device__ __forceinline__ float bff(short s) {          // bf16 bits -> f32 (exact)
    return (float)__builtin_bit_cast(__bf16, s);
}
__device__ __forceinline__ f32x4 mfma16(s16x8 a, s16x8 b, f32x4 c) {
    return __builtin_amdgcn_mfma_f32_16x16x32_bf16(a, b, c, 0, 0, 0);
}
__device__ __forceinline__ float rdlane(float v, int l) {
    return __int_as_float(__builtin_amdgcn_readlane(__float_as_int(v), l));
}
__device__ __forceinline__ void split8(f32x4 a, f32x4 b, s16x8& h, s16x8& l) {
    #pragma unroll
    for (int j = 0; j < 4; ++j) {
        short h0 = bfs(a[j]); h[j] = h0;     l[j] = bfs(a[j] - bff(h0));
        short h1 = bfs(b[j]); h[4 + j] = h1; l[4 + j] = bfs(b[j] - bff(h1));
    }
}

// B-frag loader: lane (g,r), tile col c: b[j] = w[(k0+j)*64 + c], split hi/lo.
__device__ __forceinline__ void load_bfrag(const float* __restrict__ w, int k0, int c,
                                           s16x8& hi, s16x8& lo) {
    #pragma unroll
    for (int j = 0; j < 8; ++j) {
        float f = w[(size_t)(k0 + j) * 64 + c];
        short h = bfs(f);
        hi[j] = h;
        lo[j] = bfs(f - bff(h));
    }
}

// ---------------------------------------------------------------------------
// phi via bf16 MFMA (L1: x-hi/lo x W1-hi/lo = 12 MFMA; h1 staged bf16;
// L2: h1 x W2-hi/lo = 16 MFMA). Round-11 change: CONTIGUOUS-STREAM pooling.
// Rounds 8-10 showed duration is pinned by the atomic flush path (dur tracks
// WRITE_SIZE at ~1.7us/MB; conditional atomics force vmcnt(0) drains of the
// prefetch). Old mapping gave each lane-group a 4-track window that jumped 13
// tracks per tile -> ~0.8 flushes/group/tile. New mapping: MFMA row r of
// tile t <- track wbase + (r>>2)*32 + 4t + (r&3), so each lane-group sweeps
// a contiguous 32-track stream -> flushes only at true event boundaries
// (0.2/group/tile, 4x less traffic; ~45% of tiles atomic-free).
// MFMA layouts (m89/m91-verified): A: row=l&15, k=8*(l>>4)+j; B: col=l&15,
// k=8*(l>>4)+j; C/D: col=l&15, row=4*(l>>4)+reg.  C-row 4g+q of tile t is
// track wbase + g*32 + 4t + q == group g's stream, in order.
// ---------------------------------------------------------------------------
__global__ __launch_bounds__(256, 4) void phi_mfma_kernel(
    const float* __restrict__ x,
    const int*   __restrict__ eids,
    const float* __restrict__ w1, const float* __restrict__ b1,
    const float* __restrict__ w2, const float* __restrict__ b2,
    float* __restrict__ pooled, int n_tracks)
{
    // W2 frags: [4s+n] = hi, [8+4s+n] = lo
    __shared__ s16x8 wfrag[16][64];          // 16 KB
    __shared__ short h1s[4][16 * H1W];       // bf16 h1, 2816 B per wave

    const int lane = threadIdx.x & 63;
    const int wv   = threadIdx.x >> 6;
    const int g    = lane >> 4;   // 0..3
    const int r    = lane & 15;   // 0..15
    const int sg   = r >> 2;      // stream of A-row r
    const int so   = r & 3;       // offset within the stream's 4-track window

    // ---- one-time cooperative pack of W2 frags ----
    #pragma unroll
    for (int ff = 0; ff < 4; ++ff) {
        int f   = wv + 4 * ff;
        int idx = f & 7;
        int s   = idx >> 2;
        int n   = idx & 3;
        bool lo = (f >= 8);
        s16x8 v;
        #pragma unroll
        for (int j = 0; j < 8; ++j) {
            float fv = w2[(size_t)(32 * s + 8 * g + j) * 64 + (r + 16 * n)];
            short h  = bfs(fv);
            v[j] = lo ? bfs(fv - bff(h)) : h;
        }
        wfrag[f][lane] = v;
    }
    __syncthreads();

    short* h1w = h1s[wv];
    const long long wbase = ((long long)blockIdx.x * 4 + wv) * (4LL * STREAM);
    if (wbase >= n_tracks) return;   // after the only barrier -> safe

    // ---- W1 hi/lo frags in VGPRs (32 regs) ----
    s16x8 w1h[4], w1l[4];
    #pragma unroll
    for (int n = 0; n < 4; ++n) load_bfrag(w1, 8 * g, r + 16 * n, w1h[n], w1l[n]);

    float b1v[4], b2v[4];
    #pragma unroll
    for (int n = 0; n < 4; ++n) { b1v[n] = b1[r + 16 * n]; b2v[n] = b2[r + 16 * n]; }

    // x loader: A-row r of tile T <- track wbase + sg*STREAM + 4T + so
    #define LOADX(T, XA, XB) {                                                    \
        long long row_ = wbase + (long long)sg * STREAM + 4 * (T) + so;           \
        if (row_ > n_tracks - 1) row_ = n_tracks - 1;                             \
        XA = *(const f32x4*)(x + row_ * N_FEAT + 8 * g);                          \
        XB = *(const f32x4*)(x + row_ * N_FEAT + 8 * g + 4);                      \
    }

    // ---- prologue: tile 0 x ----
    f32x4 xa, xb;
    LOADX(0, xa, xb)

    float carry[4] = {0.f, 0.f, 0.f, 0.f};
    int carry_id = -1;
    int dyn = 0;   // opaque 0: keeps wfrag reads per-tile (defeats LICM reg-hoist)

    #pragma unroll 1
    for (int t = 0; t < TILES_PER_WAVE; ++t) {
        asm volatile("" : "+v"(dyn));
        const s16x8* wfl = (const s16x8*)&wfrag[0][lane] + dyn;

        // event ids for group g's current 4-track window (contiguous stream)
        long long tbg = wbase + (long long)g * STREAM + 4 * t;   // group window base
        long long ib = tbg;
        if (ib > n_tracks - 4) ib = (n_tracks - 4) & ~3LL;
        i32x4 e4 = *(const i32x4*)(eids + ib);

        // ---- split current x to hi/lo A-frags; prefetch next tile ----
        s16x8 xh, xl;
        split8(xa, xb, xh, xl);
        if (t + 1 < TILES_PER_WAVE) LOADX(t + 1, xa, xb)

        // ---- layer 1: 12 MFMA (W1 from regs) ----
        f32x4 h1C[4];
        #pragma unroll
        for (int n = 0; n < 4; ++n) {
            f32x4 c = {0.f, 0.f, 0.f, 0.f};
            c = mfma16(xl, w1h[n], c);
            c = mfma16(xh, w1l[n], c);
            c = mfma16(xh, w1h[n], c);
            h1C[n] = c;
        }

        // ---- bias+relu, stage h1 as bf16 ----
        #pragma unroll
        for (int n = 0; n < 4; ++n)
            #pragma unroll
            for (int q = 0; q < 4; ++q)
                h1w[(4 * g + q) * H1W + r + 16 * n] =
                    bfs(fmaxf(h1C[n][q] + b1v[n], 0.f));

        // ---- read back h1 rows: 2 b128 = ready A-frags (no extraction) ----
        s16x8 ah0 = *(const s16x8*)&h1w[r * H1W + 8 * g];        // k = 0..31
        s16x8 ah1 = *(const s16x8*)&h1w[r * H1W + 32 + 8 * g];   // k = 32..63

        // ---- layer 2: 16 MFMA (W2 hi/lo frags from LDS) ----
        f32x4 h2C[4] = {{0.f,0.f,0.f,0.f},{0.f,0.f,0.f,0.f},{0.f,0.f,0.f,0.f},{0.f,0.f,0.f,0.f}};
        #pragma unroll
        for (int n = 0; n < 4; ++n) {
            h2C[n] = mfma16(ah0, wfl[64 * (8 + n)], h2C[n]);       // lo s0
            h2C[n] = mfma16(ah0, wfl[64 * n],       h2C[n]);       // hi s0
            h2C[n] = mfma16(ah1, wfl[64 * (12 + n)], h2C[n]);      // lo s1
            h2C[n] = mfma16(ah1, wfl[64 * (4 + n)],  h2C[n]);      // hi s1
        }

        // ---- bias+relu+pool: contiguous-stream run carry ----
        int remg = (int)(n_tracks - tbg);            // valid tracks in window
        remg = remg < 0 ? 0 : (remg > 4 ? 4 : remg);
        const bool newrun   = (e4[0] != carry_id);   // adjacent-track boundary
        const bool doflush0 = newrun && (carry_id >= 0);
        const bool q01 = (e4[1] != e4[0]);
        const bool q12 = (e4[2] != e4[1]);
        const bool q23 = (e4[3] != e4[2]);
        #pragma unroll
        for (int n = 0; n < 4; ++n) {
            f32x4 hv;
            #pragma unroll
            for (int q = 0; q < 4; ++q) {
                float fq = fmaxf(h2C[n][q] + b2v[n], 0.f);
                hv[q] = (q < remg) ? fq : 0.f;
            }
            float* pp = pooled + (size_t)(r + 16 * n);
            float c = carry[n];
            if (doflush0) atomicAdd(pp + (size_t)carry_id * N_LAT, c);
            if (newrun)   c = 0.f;
            c += hv[0];
            if (q01) { atomicAdd(pp + (size_t)e4[0] * N_LAT, c); c = 0.f; }
            c += hv[1];
            if (q12) { atomicAdd(pp + (size_t)e4[1] * N_LAT, c); c = 0.f; }
            c += hv[2];
            if (q23) { atomicAdd(pp + (size_t)e4[2] * N_LAT, c); c = 0.f; }
            c += hv[3];
            carry[n] = c;
        }
        carry_id = e4[3];
    }

    if (carry_id >= 0) {
        #pragma unroll
        for (int n = 0; n < 4; ++n)
            atomicAdd(pooled + (size_t)carry_id * N_LAT + r + 16 * n, carry[n]);
    }
    #undef LOADX
}

// ---------------------------------------------------------------------------
// rho, wave-parallel (unchanged this round; next optimization target).
// ---------------------------------------------------------------------------
__global__ __launch_bounds__(512) void rho_kernel(
    const float* __restrict__ pooled,
    const float* __restrict__ w1, const float* __restrict__ b1,
    const float* __restrict__ w2, const float* __restrict__ b2,
    const float* __restrict__ w3, const float* __restrict__ b3,
    float* __restrict__ out, int n_events)
{
    __shared__ float lw1[N_LAT * R_HID];
    __shared__ float lw2[R_HID * N_LAT];
    __shared__ float lbias[R_HID + N_LAT + N_LAT + 1];
    {
        int tid = threadIdx.x;
        for (int i = tid; i < N_LAT * R_HID; i += 512) lw1[i] = w1[i];
        for (int i = tid; i < R_HID * N_LAT; i += 512) lw2[i] = w2[i];
        if (tid < R_HID) lbias[tid] = b1[tid];
        if (tid < N_LAT) lbias[R_HID + tid] = b2[tid];
        if (tid < N_LAT) lbias[R_HID + N_LAT + tid] = w3[tid];
        if (tid == 0)    lbias[R_HID + 2 * N_LAT] = b3[0];
    }
    __syncthreads();

    const int lane = threadIdx.x & 63;
    const long long ebase = ((long long)blockIdx.x * 8 + (threadIdx.x >> 6)) * 8;
    if (ebase >= n_events) return;

    const float b1va = lbias[lane];
    const float b1vb = lbias[64 + lane];
    const float b2v  = lbias[R_HID + lane];
    const float w3v  = lbias[R_HID + N_LAT + lane];
    const float b3v  = lbias[R_HID + 2 * N_LAT];

    float pe[8];
    #pragma unroll
    for (int i = 0; i < 8; ++i) {
        long long e = ebase + i;
        pe[i] = (e < n_events) ? pooled[e * N_LAT + lane] : 0.f;
    }

    float r1a[8], r1b[8];
    #pragma unroll
    for (int i = 0; i < 8; ++i) { r1a[i] = b1va; r1b[i] = b1vb; }
    #pragma unroll 2
    for (int k = 0; k < N_LAT; ++k) {
        float wA = lw1[k * R_HID + lane];
        float wB = lw1[k * R_HID + 64 + lane];
        #pragma unroll
        for (int i = 0; i < 8; ++i) {
            float s = rdlane(pe[i], k);
            r1a[i] = fmaf(s, wA, r1a[i]);
            r1b[i] = fmaf(s, wB, r1b[i]);
        }
    }
    #pragma unroll
    for (int i = 0; i < 8; ++i) {
        r1a[i] = fmaxf(r1a[i], 0.f);
        r1b[i] = fmaxf(r1b[i], 0.f);
    }

    float r2[8];
    #pragma unroll
    for (int i = 0; i < 8; ++i) r2[i] = b2v;
    #pragma unroll 2
    for (int k = 0; k < 64; ++k) {
        float w = lw2[k * N_LAT + lane];
        #pragma unroll
        for (int i = 0; i < 8; ++i) r2[i] = fmaf(rdlane(r1a[i], k), w, r2[i]);
    }
    #pragma unroll 2
    for (int k = 0; k < 64; ++k) {
        float w = lw2[(64 + k) * N_LAT + lane];
        #pragma unroll
        for (int i = 0; i < 8; ++i) r2[i] = fmaf(rdlane(r1b[i], k), w, r2[i]);
    }

    float zv = 0.f;
    #pragma unroll
    for (int i = 0; i < 8; ++i) {
        float tv = fmaxf(r2[i], 0.f) * w3v;
        #pragma unroll
        for (int off = 32; off >= 1; off >>= 1) tv += __shfl_xor(tv, off, 64);
        zv = (lane == i) ? tv : zv;
    }
    if (lane < 8 && ebase + lane < n_events)
        out[ebase + lane] = 1.f / (1.f + expf(-(zv + b3v)));
}

extern "C" void kernel_launch(void* const* d_in, const int* in_sizes, int n_in,
                              void* d_out, int out_size, void* d_ws, size_t ws_size,
                              hipStream_t stream) {
    const float* x      = (const float*)d_in[0];
    const int*   eids   = (const int*)  d_in[1];
    const float* phi_w1 = (const float*)d_in[2];
    const float* phi_b1 = (const float*)d_in[3];
    const float* phi_w2 = (const float*)d_in[4];
    const float* phi_b2 = (const float*)d_in[5];
    const float* rho_w1 = (const float*)d_in[6];
    const float* rho_b1 = (const float*)d_in[7];
    const float* rho_w2 = (const float*)d_in[8];
    const float* rho_b2 = (const float*)d_in[9];
    const float* rho_w3 = (const float*)d_in[10];
    const float* rho_b3 = (const float*)d_in[11];
    float* out = (float*)d_out;

    int n_tracks = in_sizes[1];
    int n_events = out_size;

    float* pooled = (float*)d_ws;  // [n_events, 64] accumulator
    hipMemsetAsync(pooled, 0, (size_t)n_events * N_LAT * sizeof(float), stream);

    long long tracks_per_wave = 4LL * STREAM;   // 128
    long long waves  = ((long long)n_tracks + tracks_per_wave - 1) / tracks_per_wave;
    int phi_blocks   = (int)((waves + 3) / 4);
    phi_mfma_kernel<<<phi_blocks, 256, 0, stream>>>(
        x, eids, phi_w1, phi_b1, phi_w2, phi_b2, pooled, n_tracks);

    long long ewaves = ((long long)n_events + 7) / 8;
    int rho_blocks = (int)((ewaves + 7) / 8);
    rho_kernel<<<rho_blocks, 512, 0, stream>>>(
        pooled, rho_w1, rho_b1, rho_w2, rho_b2, rho_w3, rho_b3, out, n_events);
}